// Round 4
// baseline (207.921 us; speedup 1.0000x reference)
//
#include <hip/hip_runtime.h>

// Problem constants (match reference setup_inputs()).
#define Nn 50000
#define Rr 4
#define Dd 5
#define Ee 5000000
#define Bb 4
#define NRr (Nn * Rr)   // 200000
#define NDd (Nn * Dd)   // 250000
#define ZW 7814         // ceil(250000/32)=7813 (+1 guard word for ballot hi-write)
#define PBLOCKS 2048    // 8 blocks/CU x 256 CUs (no LDS -> full occupancy)

typedef int   vi4 __attribute__((ext_vector_type(4)));
typedef float vf4 __attribute__((ext_vector_type(4)));

struct P {
    const float* inputs; const float* z_buf; const float* v; const float* r;
    const float* asc1; const float* asc2; const float* psc_rise; const float* psc;
    const float* rec_w; const int* rec_rows; const int* rec_cols;
    const float* syn_decay; const float* psc_initial; const float* t_ref;
    const float* asc_amps; const float* k; const float* v_th; const float* e_l;
    const float* v_reset; const float* g; const float* decay;
    const float* current_factor; const float* vscale; const float* voffset;
    float* out; unsigned char* z_pack; unsigned* zbits;
};

// ---------------------------------------------------------------------------
// Kernel 1: pack z_buf into per-column 4-bit batch masks (250 KB, L2-resident
// for active-edge gathers) + 1-bit OR-over-batches mask zbits (31.3 KB —
// deliberately sized to fit the 32 KB per-CU L1, gating 81.5% of edges off
// the scattered L2 path; R1 proved gating from a 250 KB L2 array costs
// +9 us of TA/L2 serialization). ALSO writes the psc_rise BASE directly
// into the output:
//   out[b][5N+row] = sd*pr + inputs*pi
// so the edge atomics accumulate w*pi[row] on top (i_rec intermediate and
// its consumer kernel eliminated; i_rec enters linearly, association error
// ~1e-6, well under the 2^-7 slack we pass with).
// ---------------------------------------------------------------------------
__global__ __launch_bounds__(256) void pack_base_kernel(P p) {
    int i = blockIdx.x * 256 + threadIdx.x;
    unsigned m = 0;
    if (i < NDd) {
#pragma unroll
        for (int b = 0; b < Bb; ++b)
            if (p.z_buf[(size_t)b * NDd + i] != 0.0f) m |= (1u << b);
        p.z_pack[i] = (unsigned char)m;
    }
    unsigned long long bal = __ballot(m != 0);
    if ((i & 63) == 0 && i < NDd) {
        p.zbits[(i >> 5)]     = (unsigned)bal;
        p.zbits[(i >> 5) + 1] = (unsigned)(bal >> 32);
    }
    if (i < Bb * Nn) {
        int b = i / Nn;
        int n = i - b * Nn;
        const size_t bnr = (size_t)b * NRr + (size_t)n * 4;
        float4 pr  = *(const float4*)(p.psc_rise + bnr);
        float4 in4 = *(const float4*)(p.inputs + bnr);
        float4 sd  = *(const float4*)(p.syn_decay + (size_t)n * 4);
        float4 pi  = *(const float4*)(p.psc_initial + (size_t)n * 4);
        float4 base;
        base.x = sd.x * pr.x + in4.x * pi.x;
        base.y = sd.y * pr.y + in4.y * pi.y;
        base.z = sd.z * pr.z + in4.z * pi.z;
        base.w = sd.w * pr.w + in4.w * pi.w;
        float* ob = p.out + (size_t)b * 18 * Nn;
        *(float4*)(ob + 5 * Nn + (size_t)n * 4) = base;
    }
}

// ---------------------------------------------------------------------------
// Kernel 2: PERSISTENT-GRID edge scatter fused with all i_rec-independent
// neuron work. R4 change vs R3: the 1-bit gate is read via plain global
// loads of the 31.3 KB zbits array (L1-resident after first touch) instead
// of an LDS copy. This drops the 31.3 KB/block LDS footprint (occupancy cap
// 5 -> 8 blocks/CU, deeper outstanding-atomic queues), the per-block fill +
// __syncthreads, and all LDS bank conflicts. Gate hits stay on-CU (L1) so
// they don't contend with the atomic wall at L2/fabric.
// Edge streams (cols/rows/w, 60 MB, zero reuse) remain non-temporal.
// Output layout per batch (18*N floats):
//   [0,N)=new_z [N,2N)=out_v [2N,3N)=new_r [3N,4N)=asc1 [4N,5N)=asc2
//   [5N,9N)=psc_rise(base + edge atomics) [9N,13N)=psc [13N,18N)=shifted z_buf
// ---------------------------------------------------------------------------
__global__ __launch_bounds__(256) void edge_neuron_kernel(P p) {
    const int gtid = blockIdx.x * 256 + threadIdx.x;
    const int gsz  = gridDim.x * 256;
    const unsigned* __restrict__ zb = p.zbits;

    // ---- i_rec-independent neuron update (200k logical threads) ----
    for (int tid = gtid; tid < Bb * Nn; tid += gsz) {
        int b = tid / Nn;
        int n = tid - b * Nn;
        const size_t bn  = (size_t)b * Nn + n;
        const size_t bnr = (size_t)b * NRr + (size_t)n * 4;

        float prev_z = p.z_buf[(size_t)b * NDd + n];
        float4 pr = *(const float4*)(p.psc_rise + bnr);
        float4 pc = *(const float4*)(p.psc + bnr);
        float4 sd = *(const float4*)(p.syn_decay + (size_t)n * 4);

        float4 npc;
        npc.x = pc.x * sd.x + sd.x * pr.x;
        npc.y = pc.y * sd.y + sd.y * pr.y;
        npc.z = pc.z * sd.z + sd.z * pr.z;
        npc.w = pc.w * sd.w + sd.w * pr.w;
        float input_current = pc.x + pc.y + pc.z + pc.w;   // OLD psc

        float new_r = fmaxf(p.r[bn] + prev_z * p.t_ref[n] - 1.0f, 0.0f);

        float2 kv = *(const float2*)(p.k + (size_t)n * 2);
        float2 aa = *(const float2*)(p.asc_amps + (size_t)n * 2);
        float kk0 = 1.0f / (1.0f + expf(-kv.x));
        float kk1 = 1.0f / (1.0f + expf(-kv.y));
        float a1 = p.asc1[bn];
        float a2 = p.asc2[bn];
        float na1 = expf(-kk0) * a1 + prev_z * aa.x;
        float na2 = expf(-kk1) * a2 + prev_z * aa.y;

        float vth = p.v_th[n];
        float el  = p.e_l[n];
        float reset_current = prev_z * (p.v_reset[n] - vth);
        float c1 = input_current + a1 + a2 + p.g[n] * el;  // OLD asc
        float new_v = p.decay[n] * p.v[bn] + p.current_factor[n] * c1
                      + reset_current;
        float v_sc = (new_v - vth) / (vth - el);
        float new_z = (v_sc > 0.0f) ? 1.0f : 0.0f;
        if (new_r > 0.0f) new_z = 0.0f;
        float out_v = new_v * p.vscale[n] + p.voffset[n];

        float* ob = p.out + (size_t)b * 18 * Nn;
        ob[n]          = new_z;
        ob[Nn + n]     = out_v;
        ob[2 * Nn + n] = new_r;
        ob[3 * Nn + n] = na1;
        ob[4 * Nn + n] = na2;
        *(float4*)(ob + 9 * Nn + (size_t)n * 4) = npc;
        ob[13 * Nn + n] = new_z;
#pragma unroll
        for (int d = 0; d < Dd - 1; ++d)
            ob[14 * Nn + (size_t)d * Nn + n] =
                p.z_buf[(size_t)b * NDd + (size_t)d * Nn + n];
    }

    // ---- edge scatter (grid-stride over quads) ----
    for (int q = gtid; q < Ee / 4; q += gsz) {
        vi4 c = __builtin_nontemporal_load((const vi4*)p.rec_cols + q);
        unsigned h0 = (zb[(unsigned)c.x >> 5] >> (c.x & 31)) & 1u;
        unsigned h1 = (zb[(unsigned)c.y >> 5] >> (c.y & 31)) & 1u;
        unsigned h2 = (zb[(unsigned)c.z >> 5] >> (c.z & 31)) & 1u;
        unsigned h3 = (zb[(unsigned)c.w >> 5] >> (c.w & 31)) & 1u;
        if (h0 | h1 | h2 | h3) {
            vi4 rw = __builtin_nontemporal_load((const vi4*)p.rec_rows + q);
            vf4 w  = __builtin_nontemporal_load((const vf4*)p.rec_w + q);
            float* out5 = p.out + 5 * Nn;
            auto do_edge = [&](unsigned hh, int col, int row, float wv) {
                if (hh) {
                    unsigned mm = p.z_pack[col];
                    float s = wv * p.psc_initial[row];
                    float* o = out5 + row;
                    if (mm & 1u) atomicAdd(o, s);
                    if (mm & 2u) atomicAdd(o + 18 * Nn, s);
                    if (mm & 4u) atomicAdd(o + 36 * Nn, s);
                    if (mm & 8u) atomicAdd(o + 54 * Nn, s);
                }
            };
            do_edge(h0, c.x, rw.x, w.x);
            do_edge(h1, c.y, rw.y, w.y);
            do_edge(h2, c.z, rw.z, w.z);
            do_edge(h3, c.w, rw.w, w.w);
        }
    }
}

extern "C" void kernel_launch(void* const* d_in, const int* in_sizes, int n_in,
                              void* d_out, int out_size, void* d_ws, size_t ws_size,
                              hipStream_t stream) {
    P p;
    p.inputs        = (const float*)d_in[0];
    p.z_buf         = (const float*)d_in[1];
    p.v             = (const float*)d_in[2];
    p.r             = (const float*)d_in[3];
    p.asc1          = (const float*)d_in[4];
    p.asc2          = (const float*)d_in[5];
    p.psc_rise      = (const float*)d_in[6];
    p.psc           = (const float*)d_in[7];
    p.rec_w         = (const float*)d_in[8];
    p.rec_rows      = (const int*)d_in[9];
    p.rec_cols      = (const int*)d_in[10];
    p.syn_decay     = (const float*)d_in[11];
    p.psc_initial   = (const float*)d_in[12];
    p.t_ref         = (const float*)d_in[13];
    p.asc_amps      = (const float*)d_in[14];
    p.k             = (const float*)d_in[15];
    p.v_th          = (const float*)d_in[16];
    p.e_l           = (const float*)d_in[17];
    p.v_reset       = (const float*)d_in[18];
    p.g             = (const float*)d_in[19];
    p.decay         = (const float*)d_in[20];
    p.current_factor= (const float*)d_in[21];
    p.vscale        = (const float*)d_in[22];
    p.voffset       = (const float*)d_in[23];
    p.out           = (float*)d_out;
    // Workspace: z_pack u8[250k] @0 | zbits u32[ZW] @256000
    p.z_pack = (unsigned char*)d_ws;
    p.zbits  = (unsigned*)((char*)d_ws + 256000);

    pack_base_kernel<<<(NDd + 255) / 256, 256, 0, stream>>>(p);
    edge_neuron_kernel<<<PBLOCKS, 256, 0, stream>>>(p);
}

// Round 5
// 201.977 us; speedup vs baseline: 1.0294x; 1.0294x over previous
//
#include <hip/hip_runtime.h>

// Problem constants (match reference setup_inputs()).
#define Nn 50000
#define Rr 4
#define Dd 5
#define Ee 5000000
#define Bb 4
#define NRr (Nn * Rr)   // 200000
#define NDd (Nn * Dd)   // 250000
#define ZW2 3907        // ceil(250000/2/32): 1 bit per PAIR of columns
#define PBLOCKS 2048    // 8 blocks/CU x 256 CUs (15.6KB LDS -> wave-cap limited)

typedef int   vi4 __attribute__((ext_vector_type(4)));
typedef float vf4 __attribute__((ext_vector_type(4)));

struct P {
    const float* inputs; const float* z_buf; const float* v; const float* r;
    const float* asc1; const float* asc2; const float* psc_rise; const float* psc;
    const float* rec_w; const int* rec_rows; const int* rec_cols;
    const float* syn_decay; const float* psc_initial; const float* t_ref;
    const float* asc_amps; const float* k; const float* v_th; const float* e_l;
    const float* v_reset; const float* g; const float* decay;
    const float* current_factor; const float* vscale; const float* voffset;
    float* out; unsigned char* z_pack; unsigned* zbits;
};

// ---------------------------------------------------------------------------
// Kernel 1: pack z_buf into per-column 4-bit batch masks z_pack (250 KB,
// per-XCD-L2-resident for active-edge gathers) + PAIR-compressed 1-bit OR
// mask zbits (1 bit per 2 columns, 15.6 KB -> LDS gate in kernel 2 at
// 8 blocks/CU instead of 5). Pair false-positive rate 33.6% vs 18.5% true;
// the extra ~750K z_pack gathers are L2-local (cheap, cf. R1 scaling) and
// the mm==0 check still filters them before any atomic.
// ALSO writes the psc_rise BASE directly into the output:
//   out[b][5N+row] = sd*pr + inputs*pi
// so the edge atomics accumulate w*pi[row] on top (i_rec intermediate and
// its consumer kernel eliminated; linear contribution, association error
// ~1e-6, well under the 2^-7 slack we pass with).
// ---------------------------------------------------------------------------
__global__ __launch_bounds__(256) void pack_base_kernel(P p) {
    int i = blockIdx.x * 256 + threadIdx.x;
    unsigned m = 0;
    if (i < NDd) {
#pragma unroll
        for (int b = 0; b < Bb; ++b)
            if (p.z_buf[(size_t)b * NDd + i] != 0.0f) m |= (1u << b);
        p.z_pack[i] = (unsigned char)m;
    }
    // Pair-compress: 64 lanes (64 cols) -> 32 pair bits.
    unsigned long long bal = __ballot(m != 0);
    unsigned long long x = (bal | (bal >> 1)) & 0x5555555555555555ULL;
    x = (x | (x >> 1))  & 0x3333333333333333ULL;
    x = (x | (x >> 2))  & 0x0F0F0F0F0F0F0F0FULL;
    x = (x | (x >> 4))  & 0x00FF00FF00FF00FFULL;
    x = (x | (x >> 8))  & 0x0000FFFF0000FFFFULL;
    x = (x | (x >> 16)) & 0x00000000FFFFFFFFULL;
    if ((i & 63) == 0 && i < NDd)
        p.zbits[i >> 6] = (unsigned)x;   // word w covers cols [64w, 64w+64)

    if (i < Bb * Nn) {
        int b = i / Nn;
        int n = i - b * Nn;
        const size_t bnr = (size_t)b * NRr + (size_t)n * 4;
        float4 pr  = *(const float4*)(p.psc_rise + bnr);
        float4 in4 = *(const float4*)(p.inputs + bnr);
        float4 sd  = *(const float4*)(p.syn_decay + (size_t)n * 4);
        float4 pi  = *(const float4*)(p.psc_initial + (size_t)n * 4);
        float4 base;
        base.x = sd.x * pr.x + in4.x * pi.x;
        base.y = sd.y * pr.y + in4.y * pi.y;
        base.z = sd.z * pr.z + in4.z * pi.z;
        base.w = sd.w * pr.w + in4.w * pi.w;
        float* ob = p.out + (size_t)b * 18 * Nn;
        *(float4*)(ob + 5 * Nn + (size_t)n * 4) = base;
    }
}

// ---------------------------------------------------------------------------
// Kernel 2: PERSISTENT-GRID edge scatter (LDS pair-bit gate -> z_pack byte ->
// fire-and-forget device atomics of w*pi into the output) fused with all
// i_rec-independent neuron work. R5 change vs R3: gate LDS halved to 15.6KB
// (1 bit / 2 cols) -> 8 blocks/CU co-resident (2048 persistent blocks,
// 32 waves/CU) for deeper atomic issue. Gate probes STAY IN LDS (R4 proved
// the vector-mem path serializes wave-wide scattered gathers in the TA:
// 64->72.5us). Edge streams (cols/rows/w, 60 MB, zero reuse) non-temporal.
// Output layout per batch (18*N floats):
//   [0,N)=new_z [N,2N)=out_v [2N,3N)=new_r [3N,4N)=asc1 [4N,5N)=asc2
//   [5N,9N)=psc_rise(base + edge atomics) [9N,13N)=psc [13N,18N)=shifted z_buf
// ---------------------------------------------------------------------------
__global__ __launch_bounds__(256) void edge_neuron_kernel(P p) {
    __shared__ unsigned zb[ZW2];
    for (int t = threadIdx.x; t < ZW2; t += 256) zb[t] = p.zbits[t];
    __syncthreads();
    const int gtid = blockIdx.x * 256 + threadIdx.x;
    const int gsz  = gridDim.x * 256;

    // ---- i_rec-independent neuron update (200k logical threads) ----
    for (int tid = gtid; tid < Bb * Nn; tid += gsz) {
        int b = tid / Nn;
        int n = tid - b * Nn;
        const size_t bn  = (size_t)b * Nn + n;
        const size_t bnr = (size_t)b * NRr + (size_t)n * 4;

        float prev_z = p.z_buf[(size_t)b * NDd + n];
        float4 pr = *(const float4*)(p.psc_rise + bnr);
        float4 pc = *(const float4*)(p.psc + bnr);
        float4 sd = *(const float4*)(p.syn_decay + (size_t)n * 4);

        float4 npc;
        npc.x = pc.x * sd.x + sd.x * pr.x;
        npc.y = pc.y * sd.y + sd.y * pr.y;
        npc.z = pc.z * sd.z + sd.z * pr.z;
        npc.w = pc.w * sd.w + sd.w * pr.w;
        float input_current = pc.x + pc.y + pc.z + pc.w;   // OLD psc

        float new_r = fmaxf(p.r[bn] + prev_z * p.t_ref[n] - 1.0f, 0.0f);

        float2 kv = *(const float2*)(p.k + (size_t)n * 2);
        float2 aa = *(const float2*)(p.asc_amps + (size_t)n * 2);
        float kk0 = 1.0f / (1.0f + expf(-kv.x));
        float kk1 = 1.0f / (1.0f + expf(-kv.y));
        float a1 = p.asc1[bn];
        float a2 = p.asc2[bn];
        float na1 = expf(-kk0) * a1 + prev_z * aa.x;
        float na2 = expf(-kk1) * a2 + prev_z * aa.y;

        float vth = p.v_th[n];
        float el  = p.e_l[n];
        float reset_current = prev_z * (p.v_reset[n] - vth);
        float c1 = input_current + a1 + a2 + p.g[n] * el;  // OLD asc
        float new_v = p.decay[n] * p.v[bn] + p.current_factor[n] * c1
                      + reset_current;
        float v_sc = (new_v - vth) / (vth - el);
        float new_z = (v_sc > 0.0f) ? 1.0f : 0.0f;
        if (new_r > 0.0f) new_z = 0.0f;
        float out_v = new_v * p.vscale[n] + p.voffset[n];

        float* ob = p.out + (size_t)b * 18 * Nn;
        ob[n]          = new_z;
        ob[Nn + n]     = out_v;
        ob[2 * Nn + n] = new_r;
        ob[3 * Nn + n] = na1;
        ob[4 * Nn + n] = na2;
        *(float4*)(ob + 9 * Nn + (size_t)n * 4) = npc;
        ob[13 * Nn + n] = new_z;
#pragma unroll
        for (int d = 0; d < Dd - 1; ++d)
            ob[14 * Nn + (size_t)d * Nn + n] =
                p.z_buf[(size_t)b * NDd + (size_t)d * Nn + n];
    }

    // ---- edge scatter (grid-stride over quads) ----
    for (int q = gtid; q < Ee / 4; q += gsz) {
        vi4 c = __builtin_nontemporal_load((const vi4*)p.rec_cols + q);
        // pair gate: word = col>>6, bit = (col>>1)&31
        unsigned h0 = (zb[(unsigned)c.x >> 6] >> ((c.x >> 1) & 31)) & 1u;
        unsigned h1 = (zb[(unsigned)c.y >> 6] >> ((c.y >> 1) & 31)) & 1u;
        unsigned h2 = (zb[(unsigned)c.z >> 6] >> ((c.z >> 1) & 31)) & 1u;
        unsigned h3 = (zb[(unsigned)c.w >> 6] >> ((c.w >> 1) & 31)) & 1u;
        if (h0 | h1 | h2 | h3) {
            vi4 rw = __builtin_nontemporal_load((const vi4*)p.rec_rows + q);
            vf4 w  = __builtin_nontemporal_load((const vf4*)p.rec_w + q);
            float* out5 = p.out + 5 * Nn;
            auto do_edge = [&](unsigned hh, int col, int row, float wv) {
                if (hh) {
                    unsigned mm = p.z_pack[col];
                    if (mm) {
                        float s = wv * p.psc_initial[row];
                        float* o = out5 + row;
                        if (mm & 1u) atomicAdd(o, s);
                        if (mm & 2u) atomicAdd(o + 18 * Nn, s);
                        if (mm & 4u) atomicAdd(o + 36 * Nn, s);
                        if (mm & 8u) atomicAdd(o + 54 * Nn, s);
                    }
                }
            };
            do_edge(h0, c.x, rw.x, w.x);
            do_edge(h1, c.y, rw.y, w.y);
            do_edge(h2, c.z, rw.z, w.z);
            do_edge(h3, c.w, rw.w, w.w);
        }
    }
}

extern "C" void kernel_launch(void* const* d_in, const int* in_sizes, int n_in,
                              void* d_out, int out_size, void* d_ws, size_t ws_size,
                              hipStream_t stream) {
    P p;
    p.inputs        = (const float*)d_in[0];
    p.z_buf         = (const float*)d_in[1];
    p.v             = (const float*)d_in[2];
    p.r             = (const float*)d_in[3];
    p.asc1          = (const float*)d_in[4];
    p.asc2          = (const float*)d_in[5];
    p.psc_rise      = (const float*)d_in[6];
    p.psc           = (const float*)d_in[7];
    p.rec_w         = (const float*)d_in[8];
    p.rec_rows      = (const int*)d_in[9];
    p.rec_cols      = (const int*)d_in[10];
    p.syn_decay     = (const float*)d_in[11];
    p.psc_initial   = (const float*)d_in[12];
    p.t_ref         = (const float*)d_in[13];
    p.asc_amps      = (const float*)d_in[14];
    p.k             = (const float*)d_in[15];
    p.v_th          = (const float*)d_in[16];
    p.e_l           = (const float*)d_in[17];
    p.v_reset       = (const float*)d_in[18];
    p.g             = (const float*)d_in[19];
    p.decay         = (const float*)d_in[20];
    p.current_factor= (const float*)d_in[21];
    p.vscale        = (const float*)d_in[22];
    p.voffset       = (const float*)d_in[23];
    p.out           = (float*)d_out;
    // Workspace: z_pack u8[250k] @0 | zbits u32[ZW2] @256000
    p.z_pack = (unsigned char*)d_ws;
    p.zbits  = (unsigned*)((char*)d_ws + 256000);

    pack_base_kernel<<<(NDd + 255) / 256, 256, 0, stream>>>(p);
    edge_neuron_kernel<<<PBLOCKS, 256, 0, stream>>>(p);
}

// Round 6
// 198.298 us; speedup vs baseline: 1.0485x; 1.0186x over previous
//
#include <hip/hip_runtime.h>

// Problem constants (match reference setup_inputs()).
#define Nn 50000
#define Rr 4
#define Dd 5
#define Ee 5000000
#define Bb 4
#define NRr (Nn * Rr)   // 200000
#define NDd (Nn * Dd)   // 250000
#define ZW 7814         // ceil(250000/32)=7813 (+1 guard word for ballot hi-write)
#define PBLOCKS 1280    // 5 blocks/CU x 256 CUs -- the 31.3KB-LDS occupancy cap

typedef int   vi4 __attribute__((ext_vector_type(4)));
typedef float vf4 __attribute__((ext_vector_type(4)));

struct P {
    const float* inputs; const float* z_buf; const float* v; const float* r;
    const float* asc1; const float* asc2; const float* psc_rise; const float* psc;
    const float* rec_w; const int* rec_rows; const int* rec_cols;
    const float* syn_decay; const float* psc_initial; const float* t_ref;
    const float* asc_amps; const float* k; const float* v_th; const float* e_l;
    const float* v_reset; const float* g; const float* decay;
    const float* current_factor; const float* vscale; const float* voffset;
    float* out; unsigned char* z_pack; unsigned* zbits;
};

// ---------------------------------------------------------------------------
// BEST-MEASURED CONFIG (R3, 199.7us total / 64.0us edge). Session A/B matrix:
//   R3 LDS-exact gate @45% occ  = 64.0us   <- this kernel
//   R5 LDS-pair gate  @59% occ  = 66.5us   (occupancy no help, FP gathers +2)
//   R4 L1-global gate @58% occ  = 72.5us   (TA serialization of gathers)
//   R1 no gate        @72% occ  = 75.3us   (5M scattered L2 gathers)
// Conclusion: memory-side scattered-RMW wall (~1.0M f32 atomics, 0.79/cy/XCD)
// is the binding constraint; wave depth does not convert to atomic issue.
// ---------------------------------------------------------------------------
// Kernel 1: pack z_buf into per-column 4-bit batch masks (250 KB, L2-resident
// for active-edge gathers) + 1-bit OR-over-batches mask (31.3 KB -> LDS gate
// in kernel 2; filters 81.5% of edges off the scattered-gather path). ALSO
// writes the psc_rise BASE directly into the output:
//   out[b][5N+row] = sd*pr + inputs*pi
// so the edge atomics accumulate w*pi[row] on top (i_rec intermediate and
// its consumer kernel eliminated; linear contribution, association error
// ~1e-6, well under the 2^-7 slack we pass with).
// ---------------------------------------------------------------------------
__global__ __launch_bounds__(256) void pack_base_kernel(P p) {
    int i = blockIdx.x * 256 + threadIdx.x;
    unsigned m = 0;
    if (i < NDd) {
#pragma unroll
        for (int b = 0; b < Bb; ++b)
            if (p.z_buf[(size_t)b * NDd + i] != 0.0f) m |= (1u << b);
        p.z_pack[i] = (unsigned char)m;
    }
    unsigned long long bal = __ballot(m != 0);
    if ((i & 63) == 0 && i < NDd) {
        p.zbits[(i >> 5)]     = (unsigned)bal;
        p.zbits[(i >> 5) + 1] = (unsigned)(bal >> 32);
    }
    if (i < Bb * Nn) {
        int b = i / Nn;
        int n = i - b * Nn;
        const size_t bnr = (size_t)b * NRr + (size_t)n * 4;
        float4 pr  = *(const float4*)(p.psc_rise + bnr);
        float4 in4 = *(const float4*)(p.inputs + bnr);
        float4 sd  = *(const float4*)(p.syn_decay + (size_t)n * 4);
        float4 pi  = *(const float4*)(p.psc_initial + (size_t)n * 4);
        float4 base;
        base.x = sd.x * pr.x + in4.x * pi.x;
        base.y = sd.y * pr.y + in4.y * pi.y;
        base.z = sd.z * pr.z + in4.z * pi.z;
        base.w = sd.w * pr.w + in4.w * pi.w;
        float* ob = p.out + (size_t)b * 18 * Nn;
        *(float4*)(ob + 5 * Nn + (size_t)n * 4) = base;
    }
}

// ---------------------------------------------------------------------------
// Kernel 2: PERSISTENT-GRID edge scatter (LDS bitmask gate -> z_pack byte ->
// fire-and-forget device atomics of w*pi into the output) fused with all
// i_rec-independent neuron work. Persistent 1280 blocks (= LDS occupancy cap)
// pay the 31.3KB LDS fill once each (40 MB total vs 153 MB at 4883 blocks)
// and grid-stride over the 1.25M edge quads. Edge streams (cols/rows/w,
// 60 MB, zero reuse) use non-temporal loads so they don't evict z_pack /
// psc_initial / atomic-target lines from L2.
// Output layout per batch (18*N floats):
//   [0,N)=new_z [N,2N)=out_v [2N,3N)=new_r [3N,4N)=asc1 [4N,5N)=asc2
//   [5N,9N)=psc_rise(base + edge atomics) [9N,13N)=psc [13N,18N)=shifted z_buf
// ---------------------------------------------------------------------------
__global__ __launch_bounds__(256) void edge_neuron_kernel(P p) {
    __shared__ unsigned zb[ZW];
    for (int t = threadIdx.x; t < ZW; t += 256) zb[t] = p.zbits[t];
    __syncthreads();
    const int gtid = blockIdx.x * 256 + threadIdx.x;
    const int gsz  = gridDim.x * 256;

    // ---- i_rec-independent neuron update (200k logical threads) ----
    for (int tid = gtid; tid < Bb * Nn; tid += gsz) {
        int b = tid / Nn;
        int n = tid - b * Nn;
        const size_t bn  = (size_t)b * Nn + n;
        const size_t bnr = (size_t)b * NRr + (size_t)n * 4;

        float prev_z = p.z_buf[(size_t)b * NDd + n];
        float4 pr = *(const float4*)(p.psc_rise + bnr);
        float4 pc = *(const float4*)(p.psc + bnr);
        float4 sd = *(const float4*)(p.syn_decay + (size_t)n * 4);

        float4 npc;
        npc.x = pc.x * sd.x + sd.x * pr.x;
        npc.y = pc.y * sd.y + sd.y * pr.y;
        npc.z = pc.z * sd.z + sd.z * pr.z;
        npc.w = pc.w * sd.w + sd.w * pr.w;
        float input_current = pc.x + pc.y + pc.z + pc.w;   // OLD psc

        float new_r = fmaxf(p.r[bn] + prev_z * p.t_ref[n] - 1.0f, 0.0f);

        float2 kv = *(const float2*)(p.k + (size_t)n * 2);
        float2 aa = *(const float2*)(p.asc_amps + (size_t)n * 2);
        float kk0 = 1.0f / (1.0f + expf(-kv.x));
        float kk1 = 1.0f / (1.0f + expf(-kv.y));
        float a1 = p.asc1[bn];
        float a2 = p.asc2[bn];
        float na1 = expf(-kk0) * a1 + prev_z * aa.x;
        float na2 = expf(-kk1) * a2 + prev_z * aa.y;

        float vth = p.v_th[n];
        float el  = p.e_l[n];
        float reset_current = prev_z * (p.v_reset[n] - vth);
        float c1 = input_current + a1 + a2 + p.g[n] * el;  // OLD asc
        float new_v = p.decay[n] * p.v[bn] + p.current_factor[n] * c1
                      + reset_current;
        float v_sc = (new_v - vth) / (vth - el);
        float new_z = (v_sc > 0.0f) ? 1.0f : 0.0f;
        if (new_r > 0.0f) new_z = 0.0f;
        float out_v = new_v * p.vscale[n] + p.voffset[n];

        float* ob = p.out + (size_t)b * 18 * Nn;
        ob[n]          = new_z;
        ob[Nn + n]     = out_v;
        ob[2 * Nn + n] = new_r;
        ob[3 * Nn + n] = na1;
        ob[4 * Nn + n] = na2;
        *(float4*)(ob + 9 * Nn + (size_t)n * 4) = npc;
        ob[13 * Nn + n] = new_z;
#pragma unroll
        for (int d = 0; d < Dd - 1; ++d)
            ob[14 * Nn + (size_t)d * Nn + n] =
                p.z_buf[(size_t)b * NDd + (size_t)d * Nn + n];
    }

    // ---- edge scatter (grid-stride over quads) ----
    for (int q = gtid; q < Ee / 4; q += gsz) {
        vi4 c = __builtin_nontemporal_load((const vi4*)p.rec_cols + q);
        unsigned h0 = (zb[(unsigned)c.x >> 5] >> (c.x & 31)) & 1u;
        unsigned h1 = (zb[(unsigned)c.y >> 5] >> (c.y & 31)) & 1u;
        unsigned h2 = (zb[(unsigned)c.z >> 5] >> (c.z & 31)) & 1u;
        unsigned h3 = (zb[(unsigned)c.w >> 5] >> (c.w & 31)) & 1u;
        if (h0 | h1 | h2 | h3) {
            vi4 rw = __builtin_nontemporal_load((const vi4*)p.rec_rows + q);
            vf4 w  = __builtin_nontemporal_load((const vf4*)p.rec_w + q);
            float* out5 = p.out + 5 * Nn;
            auto do_edge = [&](unsigned hh, int col, int row, float wv) {
                if (hh) {
                    unsigned mm = p.z_pack[col];
                    float s = wv * p.psc_initial[row];
                    float* o = out5 + row;
                    if (mm & 1u) atomicAdd(o, s);
                    if (mm & 2u) atomicAdd(o + 18 * Nn, s);
                    if (mm & 4u) atomicAdd(o + 36 * Nn, s);
                    if (mm & 8u) atomicAdd(o + 54 * Nn, s);
                }
            };
            do_edge(h0, c.x, rw.x, w.x);
            do_edge(h1, c.y, rw.y, w.y);
            do_edge(h2, c.z, rw.z, w.z);
            do_edge(h3, c.w, rw.w, w.w);
        }
    }
}

extern "C" void kernel_launch(void* const* d_in, const int* in_sizes, int n_in,
                              void* d_out, int out_size, void* d_ws, size_t ws_size,
                              hipStream_t stream) {
    P p;
    p.inputs        = (const float*)d_in[0];
    p.z_buf         = (const float*)d_in[1];
    p.v             = (const float*)d_in[2];
    p.r             = (const float*)d_in[3];
    p.asc1          = (const float*)d_in[4];
    p.asc2          = (const float*)d_in[5];
    p.psc_rise      = (const float*)d_in[6];
    p.psc           = (const float*)d_in[7];
    p.rec_w         = (const float*)d_in[8];
    p.rec_rows      = (const int*)d_in[9];
    p.rec_cols      = (const int*)d_in[10];
    p.syn_decay     = (const float*)d_in[11];
    p.psc_initial   = (const float*)d_in[12];
    p.t_ref         = (const float*)d_in[13];
    p.asc_amps      = (const float*)d_in[14];
    p.k             = (const float*)d_in[15];
    p.v_th          = (const float*)d_in[16];
    p.e_l           = (const float*)d_in[17];
    p.v_reset       = (const float*)d_in[18];
    p.g             = (const float*)d_in[19];
    p.decay         = (const float*)d_in[20];
    p.current_factor= (const float*)d_in[21];
    p.vscale        = (const float*)d_in[22];
    p.voffset       = (const float*)d_in[23];
    p.out           = (float*)d_out;
    // Workspace: z_pack u8[250k] @0 | zbits u32[ZW] @256000
    p.z_pack = (unsigned char*)d_ws;
    p.zbits  = (unsigned*)((char*)d_ws + 256000);

    pack_base_kernel<<<(NDd + 255) / 256, 256, 0, stream>>>(p);
    edge_neuron_kernel<<<PBLOCKS, 256, 0, stream>>>(p);
}